// Round 8
// baseline (542.493 us; speedup 1.0000x reference)
//
#include <hip/hip_runtime.h>

typedef unsigned short u16;
typedef unsigned int u32;
typedef float f32x4 __attribute__((ext_vector_type(4)));
typedef __bf16 bf16x8 __attribute__((ext_vector_type(8)));

#define DEV static __device__ __forceinline__

DEV u16 f2bf(float f) {
  u32 u = __builtin_bit_cast(u32, f);
  u += 0x7fffu + ((u >> 16) & 1u);
  return (u16)(u >> 16);
}

DEV void gload_lds16(const void* g, void* l) {
  __builtin_amdgcn_global_load_lds(
      (const __attribute__((address_space(1))) u32*)g,
      (__attribute__((address_space(3))) u32*)l, 16, 0, 0);
}

// ---------------- convert kernels ----------------

__global__ __launch_bounds__(256) void cvt_bf16(const float* __restrict__ in,
                                                u16* __restrict__ out, int n4) {
  int i = blockIdx.x * 256 + threadIdx.x;
  const int stride = gridDim.x * 256;
  for (; i < n4; i += stride) {
    const float4 v = ((const float4*)in)[i];
    ushort4 o;
    o.x = f2bf(v.x); o.y = f2bf(v.y); o.z = f2bf(v.z); o.w = f2bf(v.w);
    ((ushort4*)out)[i] = o;
  }
}

// in [K,N] fp32 -> out [N,K] bf16 (transposed)
__global__ __launch_bounds__(256) void cvtT_bf16(const float* __restrict__ in,
                                                 u16* __restrict__ out, int K, int N) {
  int i = blockIdx.x * 256 + threadIdx.x;
  if (i >= N * K) return;
  int n = i / K, k = i - n * K;
  out[i] = f2bf(in[(long)k * N + n]);
}

// biasM[h][p] = bias_table[rel_idx[p]*12 + h], p < 2401
__global__ __launch_bounds__(256) void bias_pre(const float* __restrict__ bias_table,
                                                const int* __restrict__ rel_idx,
                                                float* __restrict__ biasM) {
  int i = blockIdx.x * 256 + threadIdx.x;
  if (i >= 12 * 2401) return;
  int h = i / 2401, p = i - h * 2401;
  biasM[i] = bias_table[rel_idx[p] * 12 + h];
}

// ---------------- 256x256 two-window BK=64 GEMM (K=768 fixed) ----------------
// LDS: 2 buffers x 64KB. Buffer: A[256 rows][64k] @0, B[256][64] @32768.
// Row layout: 128B/row, 8 slots of 16B; slot' = b ^ (row&7)  (canonical st-swizzle).
// global_load_lds dest linear; global source carries the inverse permutation.
// Per K-tile t:  [window1: all 24 ds_reads + 48 MFMA] lgkm0+SB+barrier
//                [window2: stage 4 halves of t+2 into buf[t&1] + 16 MFMA]
//                vmcnt(8) (t+1 landed; t+2 in flight) + barrier (publish t+1).
template <bool OUT_BF16>
__global__ __launch_bounds__(512, 2) void gemm256(
    const u16* __restrict__ A, const u16* __restrict__ BT,
    void* __restrict__ C, const float* __restrict__ bias,
    int M, int N, int nbn) {
  constexpr int T = 12;            // 768 / 64
  constexpr long Kb = 768 * 2;     // row stride bytes
  __shared__ alignas(16) char lds[131072];
  const int t = threadIdx.x;
  const int w = t >> 6, l = t & 63, lr = l & 15, lhi = l >> 4;
  const int wr = w >> 2, wc = w & 3;

  // bijective XCD-chunked swizzle
  const int nwg = gridDim.x;
  const int q = nwg >> 3, r = nwg & 7;
  const int xcd = blockIdx.x & 7, lid = blockIdx.x >> 3;
  const int swz = (xcd < r ? xcd * (q + 1) : r * (q + 1) + (xcd - r) * q) + lid;
  const int bm = swz / nbn, bn = swz % nbn;

  // staging source mapping: lane l of a load fills line (w*16 + j*8 + (l>>3)),
  // slot' = l&7  ->  k-chunk b = (l&7) ^ ((l>>3)&7), row = base + (l>>3).
  const int srow = w * 16 + (l >> 3);
  const int sb = (l & 7) ^ ((l >> 3) & 7);
  const char* gAs = (const char*)A + (long)(bm * 256 + srow) * Kb + sb * 16;
  const char* gBs = (const char*)BT + (long)(bn * 256 + srow) * Kb + sb * 16;
  const int ldw = w * 2048;  // (w*16) * 128B

  // stage the 4 halves of tile tt (8 loads / wave). halves: A0,A1,B0,B1.
#define STG(tt)                                                        \
  {                                                                    \
    const int bb = ((tt) & 1) * 65536;                                 \
    const long ko = (long)(tt) * 128;                                  \
    gload_lds16(gAs + ko, lds + bb + ldw);                             \
    gload_lds16(gAs + 12288 + ko, lds + bb + ldw + 1024);              \
    gload_lds16(gAs + 196608 + ko, lds + bb + 16384 + ldw);            \
    gload_lds16(gAs + 208896 + ko, lds + bb + 16384 + ldw + 1024);     \
    gload_lds16(gBs + ko, lds + bb + 32768 + ldw);                     \
    gload_lds16(gBs + 12288 + ko, lds + bb + 32768 + ldw + 1024);      \
    gload_lds16(gBs + 196608 + ko, lds + bb + 49152 + ldw);            \
    gload_lds16(gBs + 208896 + ko, lds + bb + 49152 + ldw + 1024);     \
  }
#define BAR                                  \
  asm volatile("" ::: "memory");             \
  __builtin_amdgcn_s_barrier();              \
  asm volatile("" ::: "memory")

  // frag read offsets: A row = wr*128 + mt*16 + lr, k-chunk b = ks*4 + lhi:
  // addr = row*128 + ((b ^ (row&7))<<4); row&7 == lr&7; ks toggles addr bit 6.
  const int aoffL = (wr * 128 + lr) * 128 + ((lhi ^ (lr & 7)) << 4);
  const int boffL = 32768 + (wc * 64 + lr) * 128 + ((lhi ^ (lr & 7)) << 4);

  f32x4 acc[8][4];
#pragma unroll
  for (int m = 0; m < 8; ++m)
#pragma unroll
    for (int n = 0; n < 4; ++n) acc[m][n] = (f32x4){0.f, 0.f, 0.f, 0.f};

  // prologue: stage tiles 0,1; wait tile 0 landed; publish.
  STG(0); STG(1);
  asm volatile("s_waitcnt vmcnt(8)" ::: "memory");
  BAR;

  for (int kt = 0; kt < T; ++kt) {
    const int bb = (kt & 1) * 65536;
    // ---- window 1: all reads of tile kt + 48 MFMA ----
    bf16x8 bfr[4][2];
#pragma unroll
    for (int nt = 0; nt < 4; ++nt) {
      bfr[nt][0] = *(const bf16x8*)(lds + (bb + boffL + nt * 2048));
      bfr[nt][1] = *(const bf16x8*)(lds + ((bb + boffL + nt * 2048) ^ 64));
    }
#pragma unroll
    for (int mt = 0; mt < 6; ++mt) {
      bf16x8 a0 = *(const bf16x8*)(lds + (bb + aoffL + mt * 2048));
      bf16x8 a1 = *(const bf16x8*)(lds + ((bb + aoffL + mt * 2048) ^ 64));
      __builtin_amdgcn_s_setprio(1);
#pragma unroll
      for (int nt = 0; nt < 4; ++nt) {
        acc[mt][nt] = __builtin_amdgcn_mfma_f32_16x16x32_bf16(a0, bfr[nt][0], acc[mt][nt], 0, 0, 0);
        acc[mt][nt] = __builtin_amdgcn_mfma_f32_16x16x32_bf16(a1, bfr[nt][1], acc[mt][nt], 0, 0, 0);
      }
      __builtin_amdgcn_s_setprio(0);
    }
    bf16x8 a60 = *(const bf16x8*)(lds + (bb + aoffL + 6 * 2048));
    bf16x8 a61 = *(const bf16x8*)(lds + ((bb + aoffL + 6 * 2048) ^ 64));
    bf16x8 a70 = *(const bf16x8*)(lds + (bb + aoffL + 7 * 2048));
    bf16x8 a71 = *(const bf16x8*)(lds + ((bb + aoffL + 7 * 2048) ^ 64));
    // drain ALL this wave's LDS reads before allowing overwrite (rule #18)
    asm volatile("s_waitcnt lgkmcnt(0)" ::: "memory");
    __builtin_amdgcn_sched_barrier(0);
    BAR;  // mid-barrier: every wave finished reading buf[kt&1]
    // ---- window 2: stage tile kt+2 into buf[kt&1]; finish MFMA ----
    if (kt + 2 < T) STG(kt + 2);
    __builtin_amdgcn_s_setprio(1);
#pragma unroll
    for (int nt = 0; nt < 4; ++nt) {
      acc[6][nt] = __builtin_amdgcn_mfma_f32_16x16x32_bf16(a60, bfr[nt][0], acc[6][nt], 0, 0, 0);
      acc[6][nt] = __builtin_amdgcn_mfma_f32_16x16x32_bf16(a61, bfr[nt][1], acc[6][nt], 0, 0, 0);
      acc[7][nt] = __builtin_amdgcn_mfma_f32_16x16x32_bf16(a70, bfr[nt][0], acc[7][nt], 0, 0, 0);
      acc[7][nt] = __builtin_amdgcn_mfma_f32_16x16x32_bf16(a71, bfr[nt][1], acc[7][nt], 0, 0, 0);
    }
    __builtin_amdgcn_s_setprio(0);
    // tile kt+1 must be landed by the next barrier:
    if (kt + 2 < T) {
      asm volatile("s_waitcnt vmcnt(8)" ::: "memory");
    } else {
      asm volatile("s_waitcnt vmcnt(0)" ::: "memory");
    }
    BAR;  // publish tile kt+1
  }
#undef STG
#undef BAR

  const int row0 = bm * 256 + wr * 128 + 4 * lhi;
  const int col0 = bn * 256 + wc * 64 + lr;
  if (OUT_BF16) {
    u16* Cc = (u16*)C;
#pragma unroll
    for (int m = 0; m < 8; ++m)
#pragma unroll
      for (int rr = 0; rr < 4; ++rr) {
        const long row = row0 + m * 16 + rr;
#pragma unroll
        for (int n = 0; n < 4; ++n)
          Cc[row * N + col0 + n * 16] = f2bf(acc[m][n][rr]);
      }
  } else {
    float* Cf = (float*)C;
    float bv[4];
#pragma unroll
    for (int n = 0; n < 4; ++n) bv[n] = bias[col0 + n * 16];
#pragma unroll
    for (int m = 0; m < 8; ++m)
#pragma unroll
      for (int rr = 0; rr < 4; ++rr) {
        const long row = row0 + m * 16 + rr;
#pragma unroll
        for (int n = 0; n < 4; ++n)
          Cf[row * N + col0 + n * 16] = acc[m][n][rr] + bv[n];
      }
  }
}

// ---------------- fused attention ----------------
__global__ __launch_bounds__(256) void attn_kernel(
    const u16* __restrict__ qkv,        // [B*49, 2304] bf16
    const float* __restrict__ prev,     // [B,12,49,49]
    const float* __restrict__ biasM,    // [12,49*49]
    float* __restrict__ prev_out,       // [B,12,49,49]
    u16* __restrict__ attn_out) {       // [B*49, 768] bf16
  __shared__ u16 Qs[64][72];   // aliased as Ps after QK^T
  __shared__ u16 Ks[64][72];
  __shared__ u16 VTs[64][72];
  __shared__ float SB[2432];   // prev+bias, then scores

  const int bh = blockIdx.x;
  const int b = bh / 12, h = bh % 12;
  const int t = threadIdx.x, w = t >> 6, l = t & 63, lr = l & 15, lhi = l >> 4;

  const u16* base = qkv + (long)(b * 49) * 2304 + h * 64;
  for (int idx = t; idx < 49 * 16; idx += 256) {
    const int n = idx >> 4, c4 = (idx & 15) << 2;
    const u16* rp = base + (long)n * 2304;
    ushort4 qv = *(const ushort4*)(rp + c4);
    ushort4 kv = *(const ushort4*)(rp + 768 + c4);
    ushort4 vv = *(const ushort4*)(rp + 1536 + c4);
    *(ushort4*)&Qs[n][c4] = qv;
    *(ushort4*)&Ks[n][c4] = kv;
    VTs[c4 + 0][n] = vv.x;
    VTs[c4 + 1][n] = vv.y;
    VTs[c4 + 2][n] = vv.z;
    VTs[c4 + 3][n] = vv.w;
  }
  for (int idx = t; idx < 1024; idx += 256) {
    const int j = idx & 15;
    if (j) VTs[idx >> 4][48 + j] = 0;
  }
  {
    const float* pv = prev + (long)bh * 2401;
    const float* bm = biasM + h * 2401;
    for (int i = t; i < 2401; i += 256) SB[i] = pv[i] + bm[i];
  }
  __syncthreads();

  bf16x8 af0 = *(const bf16x8*)&Qs[16 * w + lr][lhi * 8];
  bf16x8 af1 = *(const bf16x8*)&Qs[16 * w + lr][32 + lhi * 8];
  f32x4 sacc[4];
#pragma unroll
  for (int tc = 0; tc < 4; ++tc) {
    sacc[tc] = (f32x4){0.f, 0.f, 0.f, 0.f};
    bf16x8 b0 = *(const bf16x8*)&Ks[16 * tc + lr][lhi * 8];
    bf16x8 b1 = *(const bf16x8*)&Ks[16 * tc + lr][32 + lhi * 8];
    sacc[tc] = __builtin_amdgcn_mfma_f32_16x16x32_bf16(af0, b0, sacc[tc], 0, 0, 0);
    sacc[tc] = __builtin_amdgcn_mfma_f32_16x16x32_bf16(af1, b1, sacc[tc], 0, 0, 0);
  }

  u16 (*Ps)[72] = Qs;
  const int nrow0 = 16 * w + 4 * lhi;
  float rs[4];
#pragma unroll
  for (int r = 0; r < 4; ++r) {
    const int row = nrow0 + r;
    const bool rv = row < 49;
    float sv[4];
#pragma unroll
    for (int tc = 0; tc < 4; ++tc) {
      const int col = 16 * tc + lr;
      const bool valid = rv && (col < 49);
      const int sidx = (row < 49 ? row : 48) * 49 + (col < 49 ? col : 48);
      const float pb = SB[sidx];
      const float s = sacc[tc][r] * 0.125f + pb;
      if (valid) SB[sidx] = s;
      sv[tc] = valid ? s : -INFINITY;
    }
    float mx = fmaxf(fmaxf(sv[0], sv[1]), fmaxf(sv[2], sv[3]));
#pragma unroll
    for (int off = 8; off; off >>= 1) mx = fmaxf(mx, __shfl_xor(mx, off, 16));
    float e[4], sum = 0.f;
#pragma unroll
    for (int tc = 0; tc < 4; ++tc) {
      e[tc] = __expf(sv[tc] - mx);
      sum += e[tc];
    }
#pragma unroll
    for (int off = 8; off; off >>= 1) sum += __shfl_xor(sum, off, 16);
    rs[r] = 1.0f / sum;
#pragma unroll
    for (int tc = 0; tc < 4; ++tc)
      Ps[row][16 * tc + lr] = rv ? f2bf(e[tc]) : (u16)0;
  }
  __syncthreads();

  bf16x8 pf0 = *(const bf16x8*)&Ps[16 * w + lr][lhi * 8];
  bf16x8 pf1 = *(const bf16x8*)&Ps[16 * w + lr][32 + lhi * 8];
  f32x4 oacc[4];
#pragma unroll
  for (int dc = 0; dc < 4; ++dc) {
    oacc[dc] = (f32x4){0.f, 0.f, 0.f, 0.f};
    bf16x8 v0 = *(const bf16x8*)&VTs[16 * dc + lr][lhi * 8];
    bf16x8 v1 = *(const bf16x8*)&VTs[16 * dc + lr][32 + lhi * 8];
    oacc[dc] = __builtin_amdgcn_mfma_f32_16x16x32_bf16(pf0, v0, oacc[dc], 0, 0, 0);
    oacc[dc] = __builtin_amdgcn_mfma_f32_16x16x32_bf16(pf1, v1, oacc[dc], 0, 0, 0);
  }
  u16* ob = attn_out + (long)(b * 49) * 768 + h * 64;
#pragma unroll
  for (int r = 0; r < 4; ++r) {
    const int row = nrow0 + r;
    if (row < 49) {
#pragma unroll
      for (int dc = 0; dc < 4; ++dc)
        ob[(long)row * 768 + 16 * dc + lr] = f2bf(oacc[dc][r] * rs[r]);
    }
  }

  {
    float* pout = prev_out + (long)bh * 2401;
    for (int i = t; i < 2401; i += 256) pout[i] = SB[i];
  }
}

// ---------------- launch ----------------
extern "C" void kernel_launch(void* const* d_in, const int* in_sizes, int n_in,
                              void* d_out, int out_size, void* d_ws, size_t ws_size,
                              hipStream_t stream) {
  const float* x = (const float*)d_in[0];
  const float* prev = (const float*)d_in[1];
  const float* qkv_w = (const float*)d_in[2];
  const float* proj_w = (const float*)d_in[3];
  const float* proj_b = (const float*)d_in[4];
  const float* bias_table = (const float*)d_in[5];
  const int* rel_idx = (const int*)d_in[6];

  const int B = in_sizes[0] / (49 * 768);  // 1024
  const int M = B * 49;                    // 50176 = 196*256

  float* out0 = (float*)d_out;             // [M,768]
  float* out1 = out0 + (size_t)M * 768;    // [B,12,49,49]

  char* ws = (char*)d_ws;
  u16* xbf = (u16*)ws;                                     // M*768 bf16 (reused as attn_out)
  u16* qkvbf = (u16*)(ws + (size_t)M * 768 * 2);           // M*2304 bf16
  u16* qkvwT = (u16*)(ws + (size_t)M * 768 * 2 + (size_t)M * 2304 * 2);  // [2304,768]
  u16* projwT = qkvwT + 2304 * 768;                        // [768,768]
  float* biasM = (float*)(projwT + 768 * 768);             // [12,2401]

  bias_pre<<<(12 * 2401 + 255) / 256, 256, 0, stream>>>(bias_table, rel_idx, biasM);
  cvt_bf16<<<2048, 256, 0, stream>>>(x, xbf, M * 768 / 4);
  cvtT_bf16<<<(2304 * 768 + 255) / 256, 256, 0, stream>>>(qkv_w, qkvwT, 768, 2304);
  cvtT_bf16<<<(768 * 768 + 255) / 256, 256, 0, stream>>>(proj_w, projwT, 768, 768);

  gemm256<true><<<(M / 256) * (2304 / 256), 512, 0, stream>>>(
      xbf, qkvwT, qkvbf, nullptr, M, 2304, 2304 / 256);

  attn_kernel<<<B * 12, 256, 0, stream>>>(qkvbf, prev, biasM, out1, xbf);

  gemm256<false><<<(M / 256) * (768 / 256), 512, 0, stream>>>(
      xbf, projwT, out0, proj_b, M, 768, 768 / 256);
}

// Round 9
// 542.269 us; speedup vs baseline: 1.0004x; 1.0004x over previous
//
#include <hip/hip_runtime.h>

typedef unsigned short u16;
typedef unsigned int u32;
typedef float f32x4 __attribute__((ext_vector_type(4)));
typedef __bf16 bf16x8 __attribute__((ext_vector_type(8)));

#define DEV static __device__ __forceinline__

DEV u16 f2bf(float f) {
  u32 u = __builtin_bit_cast(u32, f);
  u += 0x7fffu + ((u >> 16) & 1u);
  return (u16)(u >> 16);
}

DEV void gload_lds16(const void* g, void* l) {
  __builtin_amdgcn_global_load_lds(
      (const __attribute__((address_space(1))) u32*)g,
      (__attribute__((address_space(3))) u32*)l, 16, 0, 0);
}

// ---------------- convert kernels ----------------

__global__ __launch_bounds__(256) void cvt_bf16(const float* __restrict__ in,
                                                u16* __restrict__ out, int n4) {
  int i = blockIdx.x * 256 + threadIdx.x;
  const int stride = gridDim.x * 256;
  for (; i < n4; i += stride) {
    const float4 v = ((const float4*)in)[i];
    ushort4 o;
    o.x = f2bf(v.x); o.y = f2bf(v.y); o.z = f2bf(v.z); o.w = f2bf(v.w);
    ((ushort4*)out)[i] = o;
  }
}

// in [K,N] fp32 -> out [N,K] bf16 (transposed)
__global__ __launch_bounds__(256) void cvtT_bf16(const float* __restrict__ in,
                                                 u16* __restrict__ out, int K, int N) {
  int i = blockIdx.x * 256 + threadIdx.x;
  if (i >= N * K) return;
  int n = i / K, k = i - n * K;
  out[i] = f2bf(in[(long)k * N + n]);
}

// biasM[h][p] = bias_table[rel_idx[p]*12 + h], p < 2401
__global__ __launch_bounds__(256) void bias_pre(const float* __restrict__ bias_table,
                                                const int* __restrict__ rel_idx,
                                                float* __restrict__ biasM) {
  int i = blockIdx.x * 256 + threadIdx.x;
  if (i >= 12 * 2401) return;
  int h = i / 2401, p = i - h * 2401;
  biasM[i] = bias_table[rel_idx[p] * 12 + h];
}

// ---------------- 256x256 phase-split GEMM (r5 ledger + m201 phases) ------
// LDS layout (per 32KB buffer): A = 128 lines x 128B (2 m-rows/line), B @+16384.
// Swizzle: (row, 16B-blk b) -> line = row>>1, slot = (row&1)*4+b, slot ^= line&7.
// Conflict-free (measured 0). Staging: depth-3, 4 buffers; source carries the
// inverse swizzle; global_load_lds dest linear.
// Per K-tile kt: two phases, each {ds_read frags; 2 gload_lds (half of kt+3);
// barrier; lgkmcnt(0)+sched_barrier; setprio1; 16 MFMA; setprio0; barrier}.
// Tile boundary: vmcnt(8) (tiles kt+2,kt+3 in flight; kt+1 landed) -- never 0.
template <bool OUT_BF16>
__global__ __launch_bounds__(512, 2) void gemm256(
    const u16* __restrict__ A, const u16* __restrict__ BT,
    void* __restrict__ C, const float* __restrict__ bias,
    int M, int N, int K, int nbn) {
  __shared__ alignas(16) char lds[131072];
  const int t = threadIdx.x;
  const int w = t >> 6, l = t & 63, lr = l & 15, lhi = l >> 4;
  const int wr = w >> 2, wc = w & 3;

  // bijective XCD-chunked swizzle
  const int nwg = gridDim.x;
  const int q = nwg >> 3, r = nwg & 7;
  const int xcd = blockIdx.x & 7, lid = blockIdx.x >> 3;
  const int swz = (xcd < r ? xcd * (q + 1) : r * (q + 1) + (xcd - r) * q) + lid;
  const int bm = swz / nbn, bn = swz % nbn;

  const int T = K >> 5;  // K-tiles of 32 (K=768 -> 24)
  const long Kb = (long)K * 2;

  // staging source (inverse swizzle; global_load_lds dest is linear)
  const int unswz = (l & 7) ^ (l >> 3);
  const int arow = 2 * (l >> 3) + (unswz >> 2);
  const int acolb = (unswz & 3) << 4;
  const char* gA0 = (const char*)A + (long)(bm * 256 + w * 32 + arow) * Kb + acolb;
  const char* gA1 = gA0 + 16 * Kb;
  const char* gB0 = (const char*)BT + (long)(bn * 256 + w * 32 + arow) * Kb + acolb;
  const char* gB1 = gB0 + 16 * Kb;
  const int ldA0 = w * 2048, ldA1 = w * 2048 + 1024;
  const int ldB0 = 16384 + w * 2048, ldB1 = 16384 + w * 2048 + 1024;

#define STG_A(tt)                                            \
  {                                                          \
    const int bb = ((tt) & 3) * 32768;                       \
    const long ko = (long)(tt) * 64;                         \
    gload_lds16(gA0 + ko, lds + bb + ldA0);                  \
    gload_lds16(gA1 + ko, lds + bb + ldA1);                  \
  }
#define STG_B(tt)                                            \
  {                                                          \
    const int bb = ((tt) & 3) * 32768;                       \
    const long ko = (long)(tt) * 64;                         \
    gload_lds16(gB0 + ko, lds + bb + ldB0);                  \
    gload_lds16(gB1 + ko, lds + bb + ldB1);                  \
  }
#define BAR                                  \
  asm volatile("" ::: "memory");             \
  __builtin_amdgcn_s_barrier();              \
  asm volatile("" ::: "memory")
#define LGKM0                                              \
  asm volatile("s_waitcnt lgkmcnt(0)" ::: "memory");       \
  __builtin_amdgcn_sched_barrier(0)

  // frag read offsets (swizzled; conflict-free, measured)
  const int rblk = ((((lr & 1) << 2) | lhi) ^ (lr >> 1));
  const int aoff0 = (wr * 64 + (lr >> 1)) * 128 + rblk * 16;          // + mt*1024
  const int boff0 = 16384 + (wc * 32 + (lr >> 1)) * 128 + rblk * 16;  // + nt*1024

  f32x4 acc[8][4];
#pragma unroll
  for (int m = 0; m < 8; ++m)
#pragma unroll
    for (int n = 0; n < 4; ++n) acc[m][n] = (f32x4){0.f, 0.f, 0.f, 0.f};

  // prologue: stage tiles 0,1,2; tile 0 landed; publish.
  STG_A(0); STG_B(0); STG_A(1); STG_B(1); STG_A(2); STG_B(2);
  asm volatile("s_waitcnt vmcnt(8)" ::: "memory");
  BAR;

  for (int kt = 0; kt < T; ++kt) {
    const int bb = (kt & 3) * 32768;
    const bool stg = (kt + 3) < T;
    // ================= phase 0: B all + A mt0-3 =================
    bf16x8 bfr[4], afr[4];
#pragma unroll
    for (int n = 0; n < 4; ++n)
      bfr[n] = *(const bf16x8*)(lds + bb + boff0 + n * 1024);
#pragma unroll
    for (int m = 0; m < 4; ++m)
      afr[m] = *(const bf16x8*)(lds + bb + aoff0 + m * 1024);
    if (stg) STG_A(kt + 3);
    BAR;
    LGKM0;
    __builtin_amdgcn_s_setprio(1);
#pragma unroll
    for (int m = 0; m < 4; ++m)
#pragma unroll
      for (int n = 0; n < 4; ++n)
        acc[m][n] = __builtin_amdgcn_mfma_f32_16x16x32_bf16(afr[m], bfr[n], acc[m][n], 0, 0, 0);
    __builtin_amdgcn_s_setprio(0);
    BAR;
    // ================= phase 1: A mt4-7 =================
    bf16x8 afr2[4];
#pragma unroll
    for (int m = 0; m < 4; ++m)
      afr2[m] = *(const bf16x8*)(lds + bb + aoff0 + (m + 4) * 1024);
    if (stg) STG_B(kt + 3);
    BAR;
    LGKM0;
    __builtin_amdgcn_s_setprio(1);
#pragma unroll
    for (int m = 0; m < 4; ++m)
#pragma unroll
      for (int n = 0; n < 4; ++n)
        acc[m + 4][n] = __builtin_amdgcn_mfma_f32_16x16x32_bf16(afr2[m], bfr[n], acc[m + 4][n], 0, 0, 0);
    __builtin_amdgcn_s_setprio(0);
    // tile boundary: publish kt+1 (landed: all but the <=8 in-flight loads)
    if (stg) {
      asm volatile("s_waitcnt vmcnt(8)" ::: "memory");
    } else {
      asm volatile("s_waitcnt vmcnt(0)" ::: "memory");
    }
    BAR;
  }
#undef STG_A
#undef STG_B
#undef BAR
#undef LGKM0

  const int row0 = bm * 256 + wr * 128 + 4 * lhi;
  const int col0 = bn * 256 + wc * 64 + lr;
  if (OUT_BF16) {
    u16* Cc = (u16*)C;
#pragma unroll
    for (int m = 0; m < 8; ++m)
#pragma unroll
      for (int rr = 0; rr < 4; ++rr) {
        const long row = row0 + m * 16 + rr;
#pragma unroll
        for (int n = 0; n < 4; ++n)
          Cc[row * N + col0 + n * 16] = f2bf(acc[m][n][rr]);
      }
  } else {
    float* Cf = (float*)C;
    float bv[4];
#pragma unroll
    for (int n = 0; n < 4; ++n) bv[n] = bias[col0 + n * 16];
#pragma unroll
    for (int m = 0; m < 8; ++m)
#pragma unroll
      for (int rr = 0; rr < 4; ++rr) {
        const long row = row0 + m * 16 + rr;
#pragma unroll
        for (int n = 0; n < 4; ++n)
          Cf[row * N + col0 + n * 16] = acc[m][n][rr] + bv[n];
      }
  }
}

// ---------------- fused attention ----------------
__global__ __launch_bounds__(256) void attn_kernel(
    const u16* __restrict__ qkv,        // [B*49, 2304] bf16
    const float* __restrict__ prev,     // [B,12,49,49]
    const float* __restrict__ biasM,    // [12,49*49]
    float* __restrict__ prev_out,       // [B,12,49,49]
    u16* __restrict__ attn_out) {       // [B*49, 768] bf16
  __shared__ u16 Qs[64][72];   // aliased as Ps after QK^T
  __shared__ u16 Ks[64][72];
  __shared__ u16 VTs[64][72];
  __shared__ float SB[2432];   // prev+bias, then scores

  const int bh = blockIdx.x;
  const int b = bh / 12, h = bh % 12;
  const int t = threadIdx.x, w = t >> 6, l = t & 63, lr = l & 15, lhi = l >> 4;

  const u16* base = qkv + (long)(b * 49) * 2304 + h * 64;
  for (int idx = t; idx < 49 * 16; idx += 256) {
    const int n = idx >> 4, c4 = (idx & 15) << 2;
    const u16* rp = base + (long)n * 2304;
    ushort4 qv = *(const ushort4*)(rp + c4);
    ushort4 kv = *(const ushort4*)(rp + 768 + c4);
    ushort4 vv = *(const ushort4*)(rp + 1536 + c4);
    *(ushort4*)&Qs[n][c4] = qv;
    *(ushort4*)&Ks[n][c4] = kv;
    VTs[c4 + 0][n] = vv.x;
    VTs[c4 + 1][n] = vv.y;
    VTs[c4 + 2][n] = vv.z;
    VTs[c4 + 3][n] = vv.w;
  }
  for (int idx = t; idx < 1024; idx += 256) {
    const int j = idx & 15;
    if (j) VTs[idx >> 4][48 + j] = 0;
  }
  {
    const float* pv = prev + (long)bh * 2401;
    const float* bm = biasM + h * 2401;
    for (int i = t; i < 2401; i += 256) SB[i] = pv[i] + bm[i];
  }
  __syncthreads();

  bf16x8 af0 = *(const bf16x8*)&Qs[16 * w + lr][lhi * 8];
  bf16x8 af1 = *(const bf16x8*)&Qs[16 * w + lr][32 + lhi * 8];
  f32x4 sacc[4];
#pragma unroll
  for (int tc = 0; tc < 4; ++tc) {
    sacc[tc] = (f32x4){0.f, 0.f, 0.f, 0.f};
    bf16x8 b0 = *(const bf16x8*)&Ks[16 * tc + lr][lhi * 8];
    bf16x8 b1 = *(const bf16x8*)&Ks[16 * tc + lr][32 + lhi * 8];
    sacc[tc] = __builtin_amdgcn_mfma_f32_16x16x32_bf16(af0, b0, sacc[tc], 0, 0, 0);
    sacc[tc] = __builtin_amdgcn_mfma_f32_16x16x32_bf16(af1, b1, sacc[tc], 0, 0, 0);
  }

  u16 (*Ps)[72] = Qs;
  const int nrow0 = 16 * w + 4 * lhi;
  float rs[4];
#pragma unroll
  for (int r = 0; r < 4; ++r) {
    const int row = nrow0 + r;
    const bool rv = row < 49;
    float sv[4];
#pragma unroll
    for (int tc = 0; tc < 4; ++tc) {
      const int col = 16 * tc + lr;
      const bool valid = rv && (col < 49);
      const int sidx = (row < 49 ? row : 48) * 49 + (col < 49 ? col : 48);
      const float pb = SB[sidx];
      const float s = sacc[tc][r] * 0.125f + pb;
      if (valid) SB[sidx] = s;
      sv[tc] = valid ? s : -INFINITY;
    }
    float mx = fmaxf(fmaxf(sv[0], sv[1]), fmaxf(sv[2], sv[3]));
#pragma unroll
    for (int off = 8; off; off >>= 1) mx = fmaxf(mx, __shfl_xor(mx, off, 16));
    float e[4], sum = 0.f;
#pragma unroll
    for (int tc = 0; tc < 4; ++tc) {
      e[tc] = __expf(sv[tc] - mx);
      sum += e[tc];
    }
#pragma unroll
    for (int off = 8; off; off >>= 1) sum += __shfl_xor(sum, off, 16);
    rs[r] = 1.0f / sum;
#pragma unroll
    for (int tc = 0; tc < 4; ++tc)
      Ps[row][16 * tc + lr] = rv ? f2bf(e[tc]) : (u16)0;
  }
  __syncthreads();

  bf16x8 pf0 = *(const bf16x8*)&Ps[16 * w + lr][lhi * 8];
  bf16x8 pf1 = *(const bf16x8*)&Ps[16 * w + lr][32 + lhi * 8];
  f32x4 oacc[4];
#pragma unroll
  for (int dc = 0; dc < 4; ++dc) {
    oacc[dc] = (f32x4){0.f, 0.f, 0.f, 0.f};
    bf16x8 v0 = *(const bf16x8*)&VTs[16 * dc + lr][lhi * 8];
    bf16x8 v1 = *(const bf16x8*)&VTs[16 * dc + lr][32 + lhi * 8];
    oacc[dc] = __builtin_amdgcn_mfma_f32_16x16x32_bf16(pf0, v0, oacc[dc], 0, 0, 0);
    oacc[dc] = __builtin_amdgcn_mfma_f32_16x16x32_bf16(pf1, v1, oacc[dc], 0, 0, 0);
  }
  u16* ob = attn_out + (long)(b * 49) * 768 + h * 64;
#pragma unroll
  for (int r = 0; r < 4; ++r) {
    const int row = nrow0 + r;
    if (row < 49) {
#pragma unroll
      for (int dc = 0; dc < 4; ++dc)
        ob[(long)row * 768 + 16 * dc + lr] = f2bf(oacc[dc][r] * rs[r]);
    }
  }

  {
    float* pout = prev_out + (long)bh * 2401;
    for (int i = t; i < 2401; i += 256) pout[i] = SB[i];
  }
}

// ---------------- launch ----------------
extern "C" void kernel_launch(void* const* d_in, const int* in_sizes, int n_in,
                              void* d_out, int out_size, void* d_ws, size_t ws_size,
                              hipStream_t stream) {
  const float* x = (const float*)d_in[0];
  const float* prev = (const float*)d_in[1];
  const float* qkv_w = (const float*)d_in[2];
  const float* proj_w = (const float*)d_in[3];
  const float* proj_b = (const float*)d_in[4];
  const float* bias_table = (const float*)d_in[5];
  const int* rel_idx = (const int*)d_in[6];

  const int B = in_sizes[0] / (49 * 768);  // 1024
  const int M = B * 49;                    // 50176 = 196*256

  float* out0 = (float*)d_out;             // [M,768]
  float* out1 = out0 + (size_t)M * 768;    // [B,12,49,49]

  char* ws = (char*)d_ws;
  u16* xbf = (u16*)ws;                                     // M*768 bf16 (reused as attn_out)
  u16* qkvbf = (u16*)(ws + (size_t)M * 768 * 2);           // M*2304 bf16
  u16* qkvwT = (u16*)(ws + (size_t)M * 768 * 2 + (size_t)M * 2304 * 2);  // [2304,768]
  u16* projwT = qkvwT + 2304 * 768;                        // [768,768]
  float* biasM = (float*)(projwT + 768 * 768);             // [12,2401]

  bias_pre<<<(12 * 2401 + 255) / 256, 256, 0, stream>>>(bias_table, rel_idx, biasM);
  cvt_bf16<<<2048, 256, 0, stream>>>(x, xbf, M * 768 / 4);
  cvtT_bf16<<<(2304 * 768 + 255) / 256, 256, 0, stream>>>(qkv_w, qkvwT, 768, 2304);
  cvtT_bf16<<<(768 * 768 + 255) / 256, 256, 0, stream>>>(proj_w, projwT, 768, 768);

  gemm256<true><<<(M / 256) * (2304 / 256), 512, 0, stream>>>(
      xbf, qkvwT, qkvbf, nullptr, M, 2304, 768, 2304 / 256);

  attn_kernel<<<B * 12, 256, 0, stream>>>(qkvbf, prev, biasM, out1, xbf);

  gemm256<false><<<(M / 256) * (768 / 256), 512, 0, stream>>>(
      xbf, projwT, out0, proj_b, M, 768, 768, 768 / 256);
}

// Round 10
// 473.852 us; speedup vs baseline: 1.1449x; 1.1444x over previous
//
#include <hip/hip_runtime.h>

typedef unsigned short u16;
typedef unsigned int u32;
typedef float f32x4 __attribute__((ext_vector_type(4)));
typedef __bf16 bf16x8 __attribute__((ext_vector_type(8)));

#define DEV static __device__ __forceinline__

DEV u16 f2bf(float f) {
  u32 u = __builtin_bit_cast(u32, f);
  u += 0x7fffu + ((u >> 16) & 1u);
  return (u16)(u >> 16);
}

DEV void gload_lds16(const void* g, void* l) {
  __builtin_amdgcn_global_load_lds(
      (const __attribute__((address_space(1))) u32*)g,
      (__attribute__((address_space(3))) u32*)l, 16, 0, 0);
}

// ---------------- convert kernels ----------------

__global__ __launch_bounds__(256) void cvt_bf16(const float* __restrict__ in,
                                                u16* __restrict__ out, int n4) {
  int i = blockIdx.x * 256 + threadIdx.x;
  const int stride = gridDim.x * 256;
  for (; i < n4; i += stride) {
    const float4 v = ((const float4*)in)[i];
    ushort4 o;
    o.x = f2bf(v.x); o.y = f2bf(v.y); o.z = f2bf(v.z); o.w = f2bf(v.w);
    ((ushort4*)out)[i] = o;
  }
}

// in [K,N] fp32 -> out [N,K] bf16 (transposed)
__global__ __launch_bounds__(256) void cvtT_bf16(const float* __restrict__ in,
                                                 u16* __restrict__ out, int K, int N) {
  int i = blockIdx.x * 256 + threadIdx.x;
  if (i >= N * K) return;
  int n = i / K, k = i - n * K;
  out[i] = f2bf(in[(long)k * N + n]);
}

// biasM[h][p] = bias_table[rel_idx[p]*12 + h], p < 2401
__global__ __launch_bounds__(256) void bias_pre(const float* __restrict__ bias_table,
                                                const int* __restrict__ rel_idx,
                                                float* __restrict__ biasM) {
  int i = blockIdx.x * 256 + threadIdx.x;
  if (i >= 12 * 2401) return;
  int h = i / 2401, p = i - h * 2401;
  biasM[i] = bias_table[rel_idx[p] * 12 + h];
}

// ---------------- 256x256 deep-pipelined GEMM (round-6 best: 210 us) -------
// LDS layout (per 32KB buffer): A = 128 lines x 128B (2 m-rows/line), B @+16384.
// Swizzle: (row, 16B-blk b) -> line = row>>1, slot = (row&1)*4+b, slot ^= line&7.
// Conflict-free (measured 0). Depth-3 staging, vmcnt(4) at bottom so tiles
// kt+1,kt+2 are published entering iter kt+1 -> next tile's fragments
// prefetched in-register DURING iter kt (ping-pong X/Y).
template <bool OUT_BF16>
__global__ __launch_bounds__(512, 2) void gemm256(
    const u16* __restrict__ A, const u16* __restrict__ BT,
    void* __restrict__ C, const float* __restrict__ bias,
    int M, int N, int K, int nbn) {
  __shared__ alignas(16) char lds[131072];
  const int t = threadIdx.x;
  const int w = t >> 6, l = t & 63, lr = l & 15, lhi = l >> 4;
  const int wr = w >> 2, wc = w & 3;

  // bijective XCD-chunked swizzle
  const int nwg = gridDim.x;
  const int q = nwg >> 3, r = nwg & 7;
  const int xcd = blockIdx.x & 7, lid = blockIdx.x >> 3;
  const int swz = (xcd < r ? xcd * (q + 1) : r * (q + 1) + (xcd - r) * q) + lid;
  const int bm = swz / nbn, bn = swz % nbn;

  const int T = K >> 5;  // K-tiles of 32 (K=768 -> 24, even)
  const long Kb = (long)K * 2;

  // staging source (inverse swizzle; global_load_lds dest is linear)
  const int unswz = (l & 7) ^ (l >> 3);
  const int arow = 2 * (l >> 3) + (unswz >> 2);
  const int acolb = (unswz & 3) << 4;
  const char* gA0 = (const char*)A + (long)(bm * 256 + w * 32 + arow) * Kb + acolb;
  const char* gA1 = gA0 + 16 * Kb;
  const char* gB0 = (const char*)BT + (long)(bn * 256 + w * 32 + arow) * Kb + acolb;
  const char* gB1 = gB0 + 16 * Kb;
  const int ldA0 = w * 2048, ldA1 = w * 2048 + 1024;
  const int ldB0 = 16384 + w * 2048, ldB1 = 16384 + w * 2048 + 1024;

#define STAGE(tt)                               \
  {                                             \
    const int bb = ((tt) & 3) * 32768;          \
    const long ko = (long)(tt) * 64;            \
    gload_lds16(gA0 + ko, lds + bb + ldA0);     \
    gload_lds16(gA1 + ko, lds + bb + ldA1);     \
    gload_lds16(gB0 + ko, lds + bb + ldB0);     \
    gload_lds16(gB1 + ko, lds + bb + ldB1);     \
  }
#define BAR                                  \
  asm volatile("" ::: "memory");             \
  __builtin_amdgcn_s_barrier();              \
  asm volatile("" ::: "memory")

  // frag read offsets (swizzled)
  const int rblk = ((((lr & 1) << 2) | lhi) ^ (lr >> 1));
  const int aoff0 = (wr * 64 + (lr >> 1)) * 128 + rblk * 16;          // + mt*1024
  const int boff0 = 16384 + (wc * 32 + (lr >> 1)) * 128 + rblk * 16;  // + nt*1024

  f32x4 acc[8][4];
#pragma unroll
  for (int m = 0; m < 8; ++m)
#pragma unroll
    for (int n = 0; n < 4; ++n) acc[m][n] = (f32x4){0.f, 0.f, 0.f, 0.f};
  bf16x8 afrX[4], bfrX[4], afrY[4], bfrY[4];

#define CLUSTER1(S)                                                        \
  __builtin_amdgcn_s_setprio(1);                                           \
  _Pragma("unroll") for (int m = 0; m < 4; ++m)                            \
      _Pragma("unroll") for (int n = 0; n < 4; ++n)                        \
          acc[m][n] = __builtin_amdgcn_mfma_f32_16x16x32_bf16(             \
              afr##S[m], bfr##S[n], acc[m][n], 0, 0, 0);                   \
  __builtin_amdgcn_s_setprio(0)
#define CLUSTER2(S)                                                        \
  __builtin_amdgcn_s_setprio(1);                                           \
  _Pragma("unroll") for (int m = 0; m < 4; ++m)                            \
      _Pragma("unroll") for (int n = 0; n < 4; ++n)                        \
          acc[m + 4][n] = __builtin_amdgcn_mfma_f32_16x16x32_bf16(         \
              afr2[m], bfr##S[n], acc[m + 4][n], 0, 0, 0);                 \
  __builtin_amdgcn_s_setprio(0)

#define BODY(kt, S, R)                                                     \
  {                                                                        \
    if ((kt) + 3 < T) STAGE((kt) + 3);                                     \
    const int bbc = ((kt) & 3) * 32768;                                    \
    const int nx = ((kt) + 1 < T) ? (kt) + 1 : (kt);                       \
    const int bbn = (nx & 3) * 32768;                                      \
    bf16x8 afr2[4];                                                        \
    _Pragma("unroll") for (int m = 0; m < 4; ++m)                          \
        afr2[m] = *(const bf16x8*)(lds + bbc + aoff0 + (m + 4) * 1024);    \
    CLUSTER1(S);                                                           \
    _Pragma("unroll") for (int n = 0; n < 4; ++n)                          \
        bfr##R[n] = *(const bf16x8*)(lds + bbn + boff0 + n * 1024);        \
    CLUSTER2(S);                                                           \
    _Pragma("unroll") for (int m = 0; m < 4; ++m)                          \
        afr##R[m] = *(const bf16x8*)(lds + bbn + aoff0 + m * 1024);        \
    if ((kt) + 3 < T) {                                                    \
      asm volatile("s_waitcnt vmcnt(4)" ::: "memory");                     \
    } else {                                                               \
      asm volatile("s_waitcnt vmcnt(0)" ::: "memory");                     \
    }                                                                      \
    BAR;                                                                   \
  }

  STAGE(0); STAGE(1); STAGE(2);
  asm volatile("s_waitcnt vmcnt(4)" ::: "memory");
  BAR;
#pragma unroll
  for (int n = 0; n < 4; ++n) bfrX[n] = *(const bf16x8*)(lds + boff0 + n * 1024);
#pragma unroll
  for (int m = 0; m < 4; ++m) afrX[m] = *(const bf16x8*)(lds + aoff0 + m * 1024);

  for (int i = 0; i < T / 2; ++i) {
    BODY(2 * i, X, Y);
    BODY(2 * i + 1, Y, X);
  }
#undef STAGE
#undef BAR
#undef CLUSTER1
#undef CLUSTER2
#undef BODY

  const int row0 = bm * 256 + wr * 128 + 4 * lhi;
  const int col0 = bn * 256 + wc * 64 + lr;
  if (OUT_BF16) {
    u16* Cc = (u16*)C;
#pragma unroll
    for (int m = 0; m < 8; ++m)
#pragma unroll
      for (int rr = 0; rr < 4; ++rr) {
        const long row = row0 + m * 16 + rr;
#pragma unroll
        for (int n = 0; n < 4; ++n)
          Cc[row * N + col0 + n * 16] = f2bf(acc[m][n][rr]);
      }
  } else {
    float* Cf = (float*)C;
    float bv[4];
#pragma unroll
    for (int n = 0; n < 4; ++n) bv[n] = bias[col0 + n * 16];
#pragma unroll
    for (int m = 0; m < 8; ++m)
#pragma unroll
      for (int rr = 0; rr < 4; ++rr) {
        const long row = row0 + m * 16 + rr;
#pragma unroll
        for (int n = 0; n < 4; ++n)
          Cf[row * N + col0 + n * 16] = acc[m][n][rr] + bv[n];
      }
  }
}

// ---------------- fused attention (v2: T14 async prev/bias + coalesced out) --
// one block (256 thr, 4 waves) per (b,h). N=49 padded to 64, hd=64.
// prev/bias are issued to REGISTERS after the qkv ds_writes (newest vmcnt
// entries -> staging waits don't drain them), first barrier is raw s_barrier
// with lgkmcnt(0) only, so the 20 loads stay in flight across QK^T.
__global__ __launch_bounds__(256) void attn_kernel(
    const u16* __restrict__ qkv,        // [B*49, 2304] bf16
    const float* __restrict__ prev,     // [B,12,49,49]
    const float* __restrict__ biasM,    // [12,49*49]
    float* __restrict__ prev_out,       // [B,12,49,49]
    u16* __restrict__ attn_out) {       // [B*49, 768] bf16
  __shared__ u16 Qs[64][72];   // aliased as Ps after QK^T
  __shared__ u16 Ks[64][72];   // aliased as O-repack after PV
  __shared__ u16 VTs[64][72];
  __shared__ float SB[2432];   // prev+bias, then scores

  const int bh = blockIdx.x;
  const int b = bh / 12, h = bh % 12;
  const int t = threadIdx.x, w = t >> 6, l = t & 63, lr = l & 15, lhi = l >> 4;

  // ---- stage Q,K,V^T into LDS ----
  const u16* base = qkv + (long)(b * 49) * 2304 + h * 64;
  for (int idx = t; idx < 49 * 16; idx += 256) {
    const int n = idx >> 4, c4 = (idx & 15) << 2;
    const u16* rp = base + (long)n * 2304;
    ushort4 qv = *(const ushort4*)(rp + c4);
    ushort4 kv = *(const ushort4*)(rp + 768 + c4);
    ushort4 vv = *(const ushort4*)(rp + 1536 + c4);
    *(ushort4*)&Qs[n][c4] = qv;
    *(ushort4*)&Ks[n][c4] = kv;
    VTs[c4 + 0][n] = vv.x;
    VTs[c4 + 1][n] = vv.y;
    VTs[c4 + 2][n] = vv.z;
    VTs[c4 + 3][n] = vv.w;
  }
  for (int idx = t; idx < 1024; idx += 256) {
    const int j = idx & 15;
    if (j) VTs[idx >> 4][48 + j] = 0;
  }

  // ---- issue prev/bias to registers (in flight across QK^T) ----
  float prevR[10], biasR[10];
  {
    const float* pv = prev + (long)bh * 2401;
    const float* bm = biasM + h * 2401;
#pragma unroll
    for (int k = 0; k < 10; ++k) {
      const int i = t + 256 * k;
      if (i < 2401) {
        prevR[k] = pv[i];
        biasR[k] = bm[i];
      }
    }
  }

  // raw barrier: drain only LDS writes; vmcnt (prev/bias) stays outstanding
  asm volatile("s_waitcnt lgkmcnt(0)" ::: "memory");
  __builtin_amdgcn_s_barrier();
  asm volatile("" ::: "memory");

  // ---- QK^T ----
  bf16x8 af0 = *(const bf16x8*)&Qs[16 * w + lr][lhi * 8];
  bf16x8 af1 = *(const bf16x8*)&Qs[16 * w + lr][32 + lhi * 8];
  f32x4 sacc[4];
#pragma unroll
  for (int tc = 0; tc < 4; ++tc) {
    sacc[tc] = (f32x4){0.f, 0.f, 0.f, 0.f};
    bf16x8 b0 = *(const bf16x8*)&Ks[16 * tc + lr][lhi * 8];
    bf16x8 b1 = *(const bf16x8*)&Ks[16 * tc + lr][32 + lhi * 8];
    sacc[tc] = __builtin_amdgcn_mfma_f32_16x16x32_bf16(af0, b0, sacc[tc], 0, 0, 0);
    sacc[tc] = __builtin_amdgcn_mfma_f32_16x16x32_bf16(af1, b1, sacc[tc], 0, 0, 0);
  }

  // ---- land prev/bias, build SB, publish ----
  asm volatile("s_waitcnt vmcnt(0)" ::: "memory");
#pragma unroll
  for (int k = 0; k < 10; ++k) {
    const int i = t + 256 * k;
    if (i < 2401) SB[i] = prevR[k] + biasR[k];
  }
  asm volatile("s_waitcnt lgkmcnt(0)" ::: "memory");
  __builtin_amdgcn_s_barrier();
  asm volatile("" ::: "memory");

  // ---- epilogue + softmax (LDS-only critical path) ----
  u16 (*Ps)[72] = Qs;  // alias: wave w reads only its own Q rows before writing
  const int nrow0 = 16 * w + 4 * lhi;
  float rs[4];
#pragma unroll
  for (int r = 0; r < 4; ++r) {
    const int row = nrow0 + r;
    const bool rv = row < 49;
    float sv[4];
#pragma unroll
    for (int tc = 0; tc < 4; ++tc) {
      const int col = 16 * tc + lr;
      const bool valid = rv && (col < 49);
      const int sidx = (row < 49 ? row : 48) * 49 + (col < 49 ? col : 48);
      const float pb = SB[sidx];
      const float s = sacc[tc][r] * 0.125f + pb;
      if (valid) SB[sidx] = s;
      sv[tc] = valid ? s : -INFINITY;
    }
    float mx = fmaxf(fmaxf(sv[0], sv[1]), fmaxf(sv[2], sv[3]));
#pragma unroll
    for (int off = 8; off; off >>= 1) mx = fmaxf(mx, __shfl_xor(mx, off, 16));
    float e[4], sum = 0.f;
#pragma unroll
    for (int tc = 0; tc < 4; ++tc) {
      e[tc] = __expf(sv[tc] - mx);
      sum += e[tc];
    }
#pragma unroll
    for (int off = 8; off; off >>= 1) sum += __shfl_xor(sum, off, 16);
    rs[r] = 1.0f / sum;
#pragma unroll
    for (int tc = 0; tc < 4; ++tc)
      Ps[row][16 * tc + lr] = rv ? f2bf(e[tc]) : (u16)0;
  }
  __syncthreads();

  // ---- P*V ----
  bf16x8 pf0 = *(const bf16x8*)&Ps[16 * w + lr][lhi * 8];
  bf16x8 pf1 = *(const bf16x8*)&Ps[16 * w + lr][32 + lhi * 8];
  f32x4 oacc[4];
#pragma unroll
  for (int dc = 0; dc < 4; ++dc) {
    oacc[dc] = (f32x4){0.f, 0.f, 0.f, 0.f};
    bf16x8 v0 = *(const bf16x8*)&VTs[16 * dc + lr][lhi * 8];
    bf16x8 v1 = *(const bf16x8*)&VTs[16 * dc + lr][32 + lhi * 8];
    oacc[dc] = __builtin_amdgcn_mfma_f32_16x16x32_bf16(pf0, v0, oacc[dc], 0, 0, 0);
    oacc[dc] = __builtin_amdgcn_mfma_f32_16x16x32_bf16(pf1, v1, oacc[dc], 0, 0, 0);
  }

  // ---- repack O into Ks (free after QK^T) for coalesced writes ----
#pragma unroll
  for (int r = 0; r < 4; ++r) {
    const int row = nrow0 + r;
    if (row < 49) {
#pragma unroll
      for (int dc = 0; dc < 4; ++dc)
        Ks[row][16 * dc + lr] = f2bf(oacc[dc][r] * rs[r]);
    }
  }
  __syncthreads();

  // ---- stream attn_out (128B rows via dwordx4) + prev_out ----
  {
    u16* ob = attn_out + (long)(b * 49) * 768 + h * 64;
    for (int idx = t; idx < 49 * 8; idx += 256) {
      const int row = idx >> 3, cc = (idx & 7) << 3;
      *(ulonglong2*)&ob[(long)row * 768 + cc] = *(const ulonglong2*)&Ks[row][cc];
    }
    float* pout = prev_out + (long)bh * 2401;
    for (int i = t; i < 2401; i += 256) pout[i] = SB[i];
  }
}

// ---------------- launch ----------------
extern "C" void kernel_launch(void* const* d_in, const int* in_sizes, int n_in,
                              void* d_out, int out_size, void* d_ws, size_t ws_size,
                              hipStream_t stream) {
  const float* x = (const float*)d_in[0];
  const float* prev = (const float*)d_in[1];
  const float* qkv_w = (const float*)d_in[2];
  const float* proj_w = (const float*)d_in[3];
  const float* proj_b = (const float*)d_in[4];
  const float* bias_table = (const float*)d_in[5];
  const int* rel_idx = (const int*)d_in[6];

  const int B = in_sizes[0] / (49 * 768);  // 1024
  const int M = B * 49;                    // 50176 = 196*256

  float* out0 = (float*)d_out;             // [M,768]
  float* out1 = out0 + (size_t)M * 768;    // [B,12,49,49]

  char* ws = (char*)d_ws;
  u16* xbf = (u16*)ws;                                     // M*768 bf16 (reused as attn_out)
  u16* qkvbf = (u16*)(ws + (size_t)M * 768 * 2);           // M*2304 bf16
  u16* qkvwT = (u16*)(ws + (size_t)M * 768 * 2 + (size_t)M * 2304 * 2);  // [2304,768]
  u16* projwT = qkvwT + 2304 * 768;                        // [768,768]
  float* biasM = (float*)(projwT + 768 * 768);             // [12,2401]

  bias_pre<<<(12 * 2401 + 255) / 256, 256, 0, stream>>>(bias_table, rel_idx, biasM);
  cvt_bf16<<<2048, 256, 0, stream>>>(x, xbf, M * 768 / 4);
  cvtT_bf16<<<(2304 * 768 + 255) / 256, 256, 0, stream>>>(qkv_w, qkvwT, 768, 2304);
  cvtT_bf16<<<(768 * 768 + 255) / 256, 256, 0, stream>>>(proj_w, projwT, 768, 768);

  gemm256<true><<<(M / 256) * (2304 / 256), 512, 0, stream>>>(
      xbf, qkvwT, qkvbf, nullptr, M, 2304, 768, 2304 / 256);

  attn_kernel<<<B * 12, 256, 0, stream>>>(qkvbf, prev, biasM, out1, xbf);

  gemm256<false><<<(M / 256) * (768 / 256), 512, 0, stream>>>(
      xbf, projwT, out0, proj_b, M, 768, 768, 768 / 256);
}